// Round 1
// baseline (630.114 us; speedup 1.0000x reference)
//
#include <hip/hip_runtime.h>

typedef unsigned short u16;
typedef unsigned int u32;
typedef __bf16 bf16x8 __attribute__((ext_vector_type(8)));
typedef float f32x4 __attribute__((ext_vector_type(4)));

// Problem constants
#define NTOK   8192      // B*S
#define DDIM   1024
#define NEXP   8
#define HDIM   1024
#define PAIRS  16384     // NTOK * K

// ---------------- helpers ----------------
__device__ __forceinline__ u16 f2bf(float f) {
  union { float f; u32 u; } v; v.f = f;
  u32 r = v.u + 0x7FFFu + ((v.u >> 16) & 1u);   // RNE
  return (u16)(r >> 16);
}

__device__ __forceinline__ f32x4 mfma16(bf16x8 a, bf16x8 b, f32x4 c) {
  return __builtin_amdgcn_mfma_f32_16x16x32_bf16(a, b, c, 0, 0, 0);
}

// ---------------- cast x fp32 -> bf16 ----------------
__global__ __launch_bounds__(256) void cast_x_kernel(const float* __restrict__ x,
                                                     u16* __restrict__ xb) {
  int i = blockIdx.x * 256 + threadIdx.x;      // 2097152 threads, 4 elems each
  float4 v = ((const float4*)x)[i];
  ushort4 o = make_ushort4(f2bf(v.x), f2bf(v.y), f2bf(v.z), f2bf(v.w));
  ((ushort4*)xb)[i] = o;
}

// ---------------- transpose + cast: out[c][r] = in[r][c] ----------------
__global__ __launch_bounds__(256) void transpose_cast(const float* __restrict__ in,
                                                      u16* __restrict__ out,
                                                      int R, int C,
                                                      long in_zs, long out_zs) {
  __shared__ float tile[32][33];
  long ib = (long)blockIdx.z * in_zs;
  long ob = (long)blockIdx.z * out_zs;
  int r0 = blockIdx.y * 32, c0 = blockIdx.x * 32;
  int tx = threadIdx.x & 31, ty = threadIdx.x >> 5;   // ty in [0,8)
  #pragma unroll
  for (int rr = 0; rr < 32; rr += 8)
    tile[ty + rr][tx] = in[ib + (long)(r0 + ty + rr) * C + c0 + tx];
  __syncthreads();
  #pragma unroll
  for (int rr = 0; rr < 32; rr += 8)
    out[ob + (long)(c0 + ty + rr) * R + r0 + tx] = f2bf(tile[tx][ty + rr]);
}

// ---------------- router: one block per token ----------------
__global__ __launch_bounds__(256) void router_kernel(
    const float* __restrict__ x, const float* __restrict__ rw,
    const float* __restrict__ ebias,
    int2* __restrict__ sel, float2* __restrict__ selw,
    float* __restrict__ probs_buf, float* __restrict__ lse2_buf,
    u32* __restrict__ cnt, u32* __restrict__ cnt_be) {
  int t = blockIdx.x;
  int tid = threadIdx.x;
  double acc[8];
  #pragma unroll
  for (int e = 0; e < 8; e++) acc[e] = 0.0;
  const float* xr = x + (long)t * DDIM;
  for (int d = tid; d < DDIM; d += 256) {
    double xv = (double)xr[d];
    #pragma unroll
    for (int e = 0; e < 8; e++) acc[e] += xv * (double)rw[e * DDIM + d];
  }
  #pragma unroll
  for (int e = 0; e < 8; e++) {
    #pragma unroll
    for (int off = 32; off > 0; off >>= 1)
      acc[e] += __shfl_down(acc[e], off, 64);
  }
  __shared__ double red[4][8];
  int lane = tid & 63, wv = tid >> 6;
  if (lane == 0) {
    #pragma unroll
    for (int e = 0; e < 8; e++) red[wv][e] = acc[e];
  }
  __syncthreads();
  if (tid == 0) {
    double logit[8]; float p[8]; float score[8];
    for (int e = 0; e < 8; e++) {
      logit[e] = red[0][e] + red[1][e] + red[2][e] + red[3][e];
      p[e] = (float)(1.0 / (1.0 + exp(-logit[e])));
      score[e] = p[e] + ebias[e];
      probs_buf[t * 8 + e] = p[e];
    }
    // top-2, ties -> lowest index (lax.top_k is stable)
    int i0 = 0;
    for (int e = 1; e < 8; e++) if (score[e] > score[i0]) i0 = e;
    int i1 = (i0 == 0) ? 1 : 0;
    for (int e = 0; e < 8; e++) if (e != i0 && score[e] > score[i1]) i1 = e;
    float w0 = p[i0], w1 = p[i1];
    float s = w0 + w1 + 1e-20f;
    sel[t] = make_int2(i0, i1);
    selw[t] = make_float2(w0 / s, w1 / s);
    // logsumexp of logits
    double m = logit[0];
    for (int e = 1; e < 8; e++) m = fmax(m, logit[e]);
    double se = 0.0;
    for (int e = 0; e < 8; e++) se += exp(logit[e] - m);
    double ls = m + log(se);
    lse2_buf[t] = (float)(ls * ls);
    atomicAdd(&cnt[i0], 1u); atomicAdd(&cnt[i1], 1u);
    int b = t >> 11;   // S = 2048
    atomicAdd(&cnt_be[b * 8 + i0], 1u); atomicAdd(&cnt_be[b * 8 + i1], 1u);
  }
}

// ---------------- prefix offsets (E=8) ----------------
__global__ void offsets_kernel(const u32* __restrict__ cnt, u32* __restrict__ offs,
                               u32* __restrict__ cursor) {
  if (threadIdx.x == 0 && blockIdx.x == 0) {
    u32 a = 0;
    for (int e = 0; e < 8; e++) { offs[e] = a; cursor[e] = a; a += cnt[e]; }
  }
}

// ---------------- build expert-sorted pair lists ----------------
__global__ __launch_bounds__(256) void build_lists(
    const int2* __restrict__ sel, const float2* __restrict__ selw,
    u32* __restrict__ cursor, int* __restrict__ tok_list, float* __restrict__ wt_list) {
  int t = blockIdx.x * 256 + threadIdx.x;   // 8192 tokens
  int2 s = sel[t]; float2 w = selw[t];
  u32 p0 = atomicAdd(&cursor[s.x], 1u);
  tok_list[p0] = t; wt_list[p0] = w.x;
  u32 p1 = atomicAdd(&cursor[s.y], 1u);
  tok_list[p1] = t; wt_list[p1] = w.y;
}

// ---------------- grouped GEMM: 64x64x64 tiles, 4 waves ----------------
// SECOND=false: h[slot][n] = relu(x[tok] @ w1t_e[n])^2      (A gathered via tok_list)
// SECOND=true : out[tok][n] += wt[slot] * (h[slot] @ w2t_e[n])
template <bool SECOND>
__global__ __launch_bounds__(256) void moe_gemm(
    const u16* __restrict__ A, const u16* __restrict__ Bt,
    u16* __restrict__ h_out, float* __restrict__ y_out,
    const int* __restrict__ tok_list, const float* __restrict__ wt_list,
    const u32* __restrict__ cnt, const u32* __restrict__ offs) {
  int tn = blockIdx.x & 15;        // 16 col tiles over N=1024
  int tm = blockIdx.x >> 4;        // global row-tile over all experts
  int e = 0, acct = 0;
  while (e < 8) {
    int nt = (int)((cnt[e] + 63u) >> 6);
    if (tm < acct + nt) break;
    acct += nt; e++;
  }
  if (e == 8) return;              // uniform across block
  int m0 = (tm - acct) * 64;
  int off = (int)offs[e];
  int ce  = (int)cnt[e];

  __shared__ uint4 AsU[64 * 8];    // [row][kchunk^swz], 8KB
  __shared__ uint4 BsU[64 * 8];

  f32x4 acc[2][2];
  #pragma unroll
  for (int i = 0; i < 2; i++)
    #pragma unroll
    for (int j = 0; j < 2; j++) acc[i][j] = (f32x4){0.f, 0.f, 0.f, 0.f};

  int l  = threadIdx.x & 63, wv = threadIdx.x >> 6;
  int wm = (wv >> 1) * 32, wn = (wv & 1) * 32;
  int mr = l & 15, q = l >> 4;
  int swz = mr & 7;

  for (int k0 = 0; k0 < 1024; k0 += 64) {
    #pragma unroll
    for (int it = 0; it < 2; it++) {
      int v = (int)threadIdx.x + it * 256;   // 0..511
      int r = v >> 3, c = v & 7;
      uint4 d = make_uint4(0, 0, 0, 0);
      if (SECOND) {
        d = *(const uint4*)(A + (long)(off + m0 + r) * 1024 + k0 + c * 8);
      } else {
        if (m0 + r < ce) {
          int tok = tok_list[off + m0 + r];
          d = *(const uint4*)(A + (long)tok * 1024 + k0 + c * 8);
        }
      }
      AsU[r * 8 + (c ^ (r & 7))] = d;
      uint4 db = *(const uint4*)(Bt + (long)(e * 1024 + tn * 64 + r) * 1024 + k0 + c * 8);
      BsU[r * 8 + (c ^ (r & 7))] = db;
    }
    __syncthreads();
    #pragma unroll
    for (int kk = 0; kk < 2; kk++) {
      int cg = kk * 4 + q;
      bf16x8 a0 = __builtin_bit_cast(bf16x8, AsU[(wm + mr) * 8 + (cg ^ swz)]);
      bf16x8 a1 = __builtin_bit_cast(bf16x8, AsU[(wm + 16 + mr) * 8 + (cg ^ swz)]);
      bf16x8 b0 = __builtin_bit_cast(bf16x8, BsU[(wn + mr) * 8 + (cg ^ swz)]);
      bf16x8 b1 = __builtin_bit_cast(bf16x8, BsU[(wn + 16 + mr) * 8 + (cg ^ swz)]);
      acc[0][0] = mfma16(a0, b0, acc[0][0]);
      acc[0][1] = mfma16(a0, b1, acc[0][1]);
      acc[1][0] = mfma16(a1, b0, acc[1][0]);
      acc[1][1] = mfma16(a1, b1, acc[1][1]);
    }
    __syncthreads();
  }

  // epilogue: C/D layout col=lane&15, row=(lane>>4)*4+reg  [m89-verified]
  #pragma unroll
  for (int i = 0; i < 2; i++) {
    #pragma unroll
    for (int r = 0; r < 4; r++) {
      int rr = wm + i * 16 + q * 4 + r;
      if (m0 + rr >= ce) continue;
      int slot = off + m0 + rr;
      float wgt = 0.f; int tok = 0;
      if (SECOND) { wgt = wt_list[slot]; tok = tok_list[slot]; }
      #pragma unroll
      for (int j = 0; j < 2; j++) {
        int cc = tn * 64 + wn + j * 16 + mr;
        float v = acc[i][j][r];
        if (!SECOND) {
          v = fmaxf(v, 0.f); v = v * v;
          h_out[(long)slot * 1024 + cc] = f2bf(v);
        } else {
          atomicAdd(y_out + (long)tok * 1024 + cc, v * wgt);
        }
      }
    }
  }
}

// ---------------- finalize aux losses ----------------
__global__ __launch_bounds__(256) void finalize_kernel(
    const float* __restrict__ lse2, const float* __restrict__ probs,
    const u32* __restrict__ cnt, const u32* __restrict__ cnt_be,
    float* __restrict__ out_tail) {
  __shared__ float sd[256];
  int tid = threadIdx.x;
  float s = 0.f;
  for (int i = tid; i < NTOK; i += 256) s += lse2[i];
  sd[tid] = s; __syncthreads();
  for (int st = 128; st > 0; st >>= 1) {
    if (tid < st) sd[tid] += sd[tid + st];
    __syncthreads();
  }
  float z = sd[0] / (float)NTOK;
  __syncthreads();
  // p_seq sums: pair p=(b,e) handled by 8 threads over 256 s-values each
  int p = tid & 31, part = tid >> 5;
  int b = p >> 3, e = p & 7;
  float ps = 0.f;
  for (int s2 = part * 256; s2 < (part + 1) * 256; s2++)
    ps += probs[(b * 2048 + s2) * 8 + e];
  sd[tid] = ps; __syncthreads();
  for (int st = 128; st >= 32; st >>= 1) {
    if (tid < st) sd[tid] += sd[tid + st];
    __syncthreads();
  }
  if (tid == 0) {
    float lb = 0.f, cl = 0.f;
    for (int pp = 0; pp < 32; pp++) {
      float psum = sd[pp];
      cl += psum;
      float f = (float)cnt_be[pp] / 4096.0f;   // S*K
      lb += f * (psum / 2048.0f);              // p_seq mean over S
    }
    lb = 8.0f * lb / 4.0f;                     // E * mean over B
    cl = cl / (float)NTOK;
    out_tail[0] = z;
    out_tail[1] = lb;
    out_tail[2] = cl;
    for (int e2 = 0; e2 < 8; e2++) out_tail[3 + e2] = (float)cnt[e2] / 16384.0f;
  }
}

// ---------------- launch ----------------
extern "C" void kernel_launch(void* const* d_in, const int* in_sizes, int n_in,
                              void* d_out, int out_size, void* d_ws, size_t ws_size,
                              hipStream_t stream) {
  const float* x     = (const float*)d_in[0];
  const float* rw    = (const float*)d_in[1];
  const float* w1    = (const float*)d_in[2];
  const float* w2    = (const float*)d_in[3];
  const float* ebias = (const float*)d_in[4];
  float* out = (float*)d_out;

  char* ws = (char*)d_ws;
  // ws layout (bytes)                                   size
  u16*    xb        = (u16*)(ws + 0);                 // 16,777,216
  u16*    w1t       = (u16*)(ws + 16777216);          // 16,777,216
  u16*    w2t       = (u16*)(ws + 33554432);          // 16,777,216
  u16*    h         = (u16*)(ws + 50331648);          // 33,554,432
  int*    tok_list  = (int*)(ws + 83886080);          // 65,536
  float*  wt_list   = (float*)(ws + 83951616);        // 65,536
  int2*   sel       = (int2*)(ws + 84017152);         // 65,536
  float2* selw      = (float2*)(ws + 84082688);       // 65,536
  float*  probs_buf = (float*)(ws + 84148224);        // 262,144
  float*  lse2_buf  = (float*)(ws + 84410368);        // 32,768
  u32*    cnt       = (u32*)(ws + 84443136);          // counters block (256 B)
  u32*    cursor    = cnt + 8;
  u32*    cnt_be    = cnt + 16;   // 32 entries [B][E]
  u32*    offs      = cnt + 48;

  hipMemsetAsync(d_out, 0, (size_t)out_size * sizeof(float), stream);
  hipMemsetAsync(cnt, 0, 256, stream);

  cast_x_kernel<<<8192, 256, 0, stream>>>(x, xb);
  // w1 [D=1024][EH=8192] -> w1t [EH][D]
  transpose_cast<<<dim3(256, 32, 1), 256, 0, stream>>>(w1, w1t, 1024, 8192, 0, 0);
  // w2 [E][H=1024][D=1024] -> w2t [E][D][H]
  transpose_cast<<<dim3(32, 32, 8), 256, 0, stream>>>(w2, w2t, 1024, 1024, 1048576L, 1048576L);
  router_kernel<<<8192, 256, 0, stream>>>(x, rw, ebias, sel, selw, probs_buf, lse2_buf, cnt, cnt_be);
  offsets_kernel<<<1, 64, 0, stream>>>(cnt, offs, cursor);
  build_lists<<<32, 256, 0, stream>>>(sel, selw, cursor, tok_list, wt_list);
  // worst case sum(ceil(cnt_e/64)) <= 263 row tiles; 16 col tiles
  moe_gemm<false><<<264 * 16, 256, 0, stream>>>(xb, w1t, h, nullptr, tok_list, wt_list, cnt, offs);
  moe_gemm<true><<<264 * 16, 256, 0, stream>>>(h, w2t, nullptr, out, tok_list, wt_list, cnt, offs);
  finalize_kernel<<<1, 256, 0, stream>>>(lse2_buf, probs_buf, cnt, cnt_be, out + 8388608);
}

// Round 2
// 508.836 us; speedup vs baseline: 1.2383x; 1.2383x over previous
//
#include <hip/hip_runtime.h>

typedef unsigned short u16;
typedef unsigned int u32;
typedef __bf16 bf16x8 __attribute__((ext_vector_type(8)));
typedef float f32x4 __attribute__((ext_vector_type(4)));

// Problem constants
#define NTOK   8192      // B*S
#define DDIM   1024
#define NEXP   8
#define HDIM   1024
#define PAIRS  16384     // NTOK * K

// ---------------- helpers ----------------
__device__ __forceinline__ u16 f2bf(float f) {
  union { float f; u32 u; } v; v.f = f;
  u32 r = v.u + 0x7FFFu + ((v.u >> 16) & 1u);   // RNE
  return (u16)(r >> 16);
}

__device__ __forceinline__ f32x4 mfma16(bf16x8 a, bf16x8 b, f32x4 c) {
  return __builtin_amdgcn_mfma_f32_16x16x32_bf16(a, b, c, 0, 0, 0);
}

// async global->LDS gather DMA, 16B per lane, lds dst = base + lane*16
__device__ __forceinline__ void gload16(const void* g, void* l) {
  __builtin_amdgcn_global_load_lds(
      (__attribute__((address_space(1))) void*)g,
      (__attribute__((address_space(3))) void*)l, 16, 0, 0);
}

// ---------------- transpose + cast: out[c][r] = in[r][c] ----------------
__global__ __launch_bounds__(256) void transpose_cast(const float* __restrict__ in,
                                                      u16* __restrict__ out,
                                                      int R, int C,
                                                      long in_zs, long out_zs) {
  __shared__ float tile[32][33];
  long ib = (long)blockIdx.z * in_zs;
  long ob = (long)blockIdx.z * out_zs;
  int r0 = blockIdx.y * 32, c0 = blockIdx.x * 32;
  int tx = threadIdx.x & 31, ty = threadIdx.x >> 5;   // ty in [0,8)
  #pragma unroll
  for (int rr = 0; rr < 32; rr += 8)
    tile[ty + rr][tx] = in[ib + (long)(r0 + ty + rr) * C + c0 + tx];
  __syncthreads();
  #pragma unroll
  for (int rr = 0; rr < 32; rr += 8)
    out[ob + (long)(c0 + ty + rr) * R + r0 + tx] = f2bf(tile[tx][ty + rr]);
}

// ---------------- router: 32 tokens/block, thread = (token, expert) ----------------
// Also emits xb (bf16 cast of x) from the e==0 lanes.
__global__ __launch_bounds__(256) void router_kernel(
    const float* __restrict__ x, const float* __restrict__ rw,
    const float* __restrict__ ebias, u16* __restrict__ xb,
    int2* __restrict__ sel, float2* __restrict__ selw,
    float* __restrict__ probs_buf, float* __restrict__ lse2_buf,
    u32* __restrict__ cnt, u32* __restrict__ cnt_be) {
  __shared__ float rw_lds[8 * 1028];    // +4 pad: breaks 8-way bank conflict
  __shared__ double lg[32][8];
  __shared__ u32 cl[8];
  int tid = threadIdx.x;
  int tl = tid >> 3, e = tid & 7;
  int t = blockIdx.x * 32 + tl;

  for (int i = tid; i < 8192; i += 256)
    rw_lds[(i >> 10) * 1028 + (i & 1023)] = rw[i];
  if (tid < 8) cl[tid] = 0;
  __syncthreads();

  const float* xr = x + (long)t * DDIM;
  const float* wr = rw_lds + e * 1028;
  u16* xbr = xb + (long)t * DDIM;
  double acc = 0.0;
  for (int d0 = 0; d0 < 1024; d0 += 16) {
    #pragma unroll
    for (int u = 0; u < 4; u++) {
      int d = d0 + u * 4;
      float4 xv = *(const float4*)(xr + d);
      float4 wv = *(const float4*)(wr + d);
      acc += (double)xv.x * (double)wv.x;
      acc += (double)xv.y * (double)wv.y;
      acc += (double)xv.z * (double)wv.z;
      acc += (double)xv.w * (double)wv.w;
      if (e == 0)
        *(ushort4*)(xbr + d) = make_ushort4(f2bf(xv.x), f2bf(xv.y), f2bf(xv.z), f2bf(xv.w));
    }
  }
  lg[tl][e] = acc;
  __syncthreads();

  if (tid < 32) {
    int t2 = blockIdx.x * 32 + tid;
    double logit[8]; float p[8]; float score[8];
    for (int ee = 0; ee < 8; ee++) {
      logit[ee] = lg[tid][ee];
      p[ee] = (float)(1.0 / (1.0 + exp(-logit[ee])));
      score[ee] = p[ee] + ebias[ee];
      probs_buf[t2 * 8 + ee] = p[ee];
    }
    // top-2, ties -> lowest index (lax.top_k is stable)
    int i0 = 0;
    for (int ee = 1; ee < 8; ee++) if (score[ee] > score[i0]) i0 = ee;
    int i1 = (i0 == 0) ? 1 : 0;
    for (int ee = 0; ee < 8; ee++) if (ee != i0 && score[ee] > score[i1]) i1 = ee;
    float w0 = p[i0], w1 = p[i1];
    float s = w0 + w1 + 1e-20f;
    sel[t2] = make_int2(i0, i1);
    selw[t2] = make_float2(w0 / s, w1 / s);
    double m = logit[0];
    for (int ee = 1; ee < 8; ee++) m = fmax(m, logit[ee]);
    double se = 0.0;
    for (int ee = 0; ee < 8; ee++) se += exp(logit[ee] - m);
    double ls = m + log(se);
    lse2_buf[t2] = (float)(ls * ls);
    atomicAdd(&cl[i0], 1u); atomicAdd(&cl[i1], 1u);
  }
  __syncthreads();
  if (tid < 8) {
    int b = (blockIdx.x * 32) >> 11;   // S = 2048, uniform per block
    atomicAdd(&cnt[tid], cl[tid]);
    atomicAdd(&cnt_be[b * 8 + tid], cl[tid]);
  }
}

// ---------------- prefix offsets (E=8) ----------------
__global__ void offsets_kernel(const u32* __restrict__ cnt, u32* __restrict__ offs,
                               u32* __restrict__ cursor) {
  if (threadIdx.x == 0 && blockIdx.x == 0) {
    u32 a = 0;
    for (int e = 0; e < 8; e++) { offs[e] = a; cursor[e] = a; a += cnt[e]; }
  }
}

// ---------------- build expert-sorted pair lists ----------------
__global__ __launch_bounds__(256) void build_lists(
    const int2* __restrict__ sel, const float2* __restrict__ selw,
    u32* __restrict__ cursor, int* __restrict__ tok_list, float* __restrict__ wt_list) {
  int t = blockIdx.x * 256 + threadIdx.x;   // 8192 tokens
  int2 s = sel[t]; float2 w = selw[t];
  u32 p0 = atomicAdd(&cursor[s.x], 1u);
  tok_list[p0] = t; wt_list[p0] = w.x;
  u32 p1 = atomicAdd(&cursor[s.y], 1u);
  tok_list[p1] = t; wt_list[p1] = w.y;
}

// ---------------- grouped GEMM: 128x128x64 tiles, 4 waves at 64x64 ----------------
// m97 structure: global_load_lds width=16 staging, XOR-swizzle applied to the
// GLOBAL gather addresses (LDS dst is wave-uniform-base + lane*16, fixed order).
// SECOND=false: h[slot][n] = relu(x[tok] @ w1t_e[n])^2      (A gathered via tok_list)
// SECOND=true : out[tok][n] += wt[slot] * (h[slot] @ w2t_e[n])
template <bool SECOND>
__global__ __launch_bounds__(256) void moe_gemm(
    const u16* __restrict__ A, const u16* __restrict__ Bt,
    u16* __restrict__ h_out, float* __restrict__ y_out,
    const int* __restrict__ tok_list, const float* __restrict__ wt_list,
    const u32* __restrict__ cnt, const u32* __restrict__ offs) {
  int tn = blockIdx.x & 7;         // 8 col tiles over N=1024
  int tm = blockIdx.x >> 3;        // global row-tile over all experts
  int e = 0, acct = 0;
  while (e < 8) {
    int nt = (int)((cnt[e] + 127u) >> 7);
    if (tm < acct + nt) break;
    acct += nt; e++;
  }
  if (e == 8) return;              // uniform across block
  int m0 = (tm - acct) * 128;
  int off = (int)offs[e];
  int ce  = (int)cnt[e];

  __shared__ uint4 As[1024];       // [row][chunk ^ (row&7)], 16 KB
  __shared__ uint4 Bs[1024];

  int tid = threadIdx.x;
  int l = tid & 63, w = tid >> 6;

  // staging gather pointers: 4 A-issues + 4 B-issues per wave, advance 64 elem/K-iter
  const u16* agp[4]; const u16* bgp[4];
  #pragma unroll
  for (int j = 0; j < 4; j++) {
    int p = w * 256 + j * 64 + l;      // physical LDS uint4 slot
    int row = p >> 3, c = p & 7;
    int lc = c ^ (row & 7);            // logical k-chunk (source-side swizzle)
    long arow;
    if (SECOND) {
      arow = (long)(off + m0 + row);
    } else {
      int rr = m0 + row; if (rr > ce - 1) rr = ce - 1;   // clamp padded rows
      arow = (long)tok_list[off + rr];
    }
    agp[j] = A + arow * 1024 + lc * 8;
    bgp[j] = Bt + (long)e * 1048576 + (long)(tn * 128 + row) * 1024 + lc * 8;
  }

  f32x4 acc[4][4];
  #pragma unroll
  for (int i = 0; i < 4; i++)
    #pragma unroll
    for (int j = 0; j < 4; j++) acc[i][j] = (f32x4){0.f, 0.f, 0.f, 0.f};

  int mr = l & 15, q = l >> 4, swz = mr & 7;
  int wm = (w >> 1) * 64, wn = (w & 1) * 64;

  for (int k0 = 0; k0 < 1024; k0 += 64) {
    #pragma unroll
    for (int j = 0; j < 4; j++) {
      gload16(agp[j], &As[w * 256 + j * 64]);
      gload16(bgp[j], &Bs[w * 256 + j * 64]);
      agp[j] += 64; bgp[j] += 64;
    }
    __syncthreads();
    #pragma unroll
    for (int kk = 0; kk < 2; kk++) {
      int cg = kk * 4 + q;
      bf16x8 af[4], bfr[4];
      #pragma unroll
      for (int i = 0; i < 4; i++) {
        af[i]  = __builtin_bit_cast(bf16x8, As[(wm + i * 16 + mr) * 8 + (cg ^ swz)]);
        bfr[i] = __builtin_bit_cast(bf16x8, Bs[(wn + i * 16 + mr) * 8 + (cg ^ swz)]);
      }
      #pragma unroll
      for (int i = 0; i < 4; i++)
        #pragma unroll
        for (int j = 0; j < 4; j++)
          acc[i][j] = mfma16(af[i], bfr[j], acc[i][j]);
    }
    __syncthreads();
  }

  // epilogue: C/D layout col=lane&15, row=(lane>>4)*4+reg  [m89-verified]
  #pragma unroll
  for (int i = 0; i < 4; i++) {
    #pragma unroll
    for (int r = 0; r < 4; r++) {
      int rr = wm + i * 16 + q * 4 + r;
      if (m0 + rr >= ce) continue;
      int slot = off + m0 + rr;
      float wgt = 0.f; int tok = 0;
      if (SECOND) { wgt = wt_list[slot]; tok = tok_list[slot]; }
      #pragma unroll
      for (int j = 0; j < 4; j++) {
        int cc = tn * 128 + wn + j * 16 + mr;
        float v = acc[i][j][r];
        if (!SECOND) {
          v = fmaxf(v, 0.f); v = v * v;
          h_out[(long)slot * 1024 + cc] = f2bf(v);
        } else {
          atomicAdd(y_out + (long)tok * 1024 + cc, v * wgt);
        }
      }
    }
  }
}

// ---------------- finalize aux losses ----------------
__global__ __launch_bounds__(256) void finalize_kernel(
    const float* __restrict__ lse2, const float* __restrict__ probs,
    const u32* __restrict__ cnt, const u32* __restrict__ cnt_be,
    float* __restrict__ out_tail) {
  __shared__ float sd[256];
  int tid = threadIdx.x;
  float s = 0.f;
  for (int i = tid; i < NTOK; i += 256) s += lse2[i];
  sd[tid] = s; __syncthreads();
  for (int st = 128; st > 0; st >>= 1) {
    if (tid < st) sd[tid] += sd[tid + st];
    __syncthreads();
  }
  float z = sd[0] / (float)NTOK;
  __syncthreads();
  // p_seq sums: pair p=(b,e) handled by 8 threads over 256 s-values each
  int p = tid & 31, part = tid >> 5;
  int b = p >> 3, e = p & 7;
  float ps = 0.f;
  for (int s2 = part * 256; s2 < (part + 1) * 256; s2++)
    ps += probs[(b * 2048 + s2) * 8 + e];
  sd[tid] = ps; __syncthreads();
  for (int st = 128; st >= 32; st >>= 1) {
    if (tid < st) sd[tid] += sd[tid + st];
    __syncthreads();
  }
  if (tid == 0) {
    float lb = 0.f, cl = 0.f;
    for (int pp = 0; pp < 32; pp++) {
      float psum = sd[pp];
      cl += psum;
      float f = (float)cnt_be[pp] / 4096.0f;   // S*K
      lb += f * (psum / 2048.0f);              // p_seq mean over S
    }
    lb = 8.0f * lb / 4.0f;                     // E * mean over B
    cl = cl / (float)NTOK;
    out_tail[0] = z;
    out_tail[1] = lb;
    out_tail[2] = cl;
    for (int e2 = 0; e2 < 8; e2++) out_tail[3 + e2] = (float)cnt[e2] / 16384.0f;
  }
}

// ---------------- launch ----------------
extern "C" void kernel_launch(void* const* d_in, const int* in_sizes, int n_in,
                              void* d_out, int out_size, void* d_ws, size_t ws_size,
                              hipStream_t stream) {
  const float* x     = (const float*)d_in[0];
  const float* rw    = (const float*)d_in[1];
  const float* w1    = (const float*)d_in[2];
  const float* w2    = (const float*)d_in[3];
  const float* ebias = (const float*)d_in[4];
  float* out = (float*)d_out;

  char* ws = (char*)d_ws;
  // ws layout (bytes)
  u16*    xb        = (u16*)(ws + 0);                 // 16,777,216
  u16*    w1t       = (u16*)(ws + 16777216);          // 16,777,216
  u16*    w2t       = (u16*)(ws + 33554432);          // 16,777,216
  u16*    h         = (u16*)(ws + 50331648);          // 16512 rows: 33,816,576
  int*    tok_list  = (int*)(ws + 84148224);          // 65,536
  float*  wt_list   = (float*)(ws + 84213760);        // 65,536
  int2*   sel       = (int2*)(ws + 84279296);         // 65,536
  float2* selw      = (float2*)(ws + 84344832);       // 65,536
  float*  probs_buf = (float*)(ws + 84410368);        // 262,144
  float*  lse2_buf  = (float*)(ws + 84672512);        // 32,768
  u32*    cnt       = (u32*)(ws + 84705280);          // counters block (256 B)
  u32*    cursor    = cnt + 8;
  u32*    cnt_be    = cnt + 16;   // 32 entries [B][E]
  u32*    offs      = cnt + 48;

  hipMemsetAsync(d_out, 0, (size_t)out_size * sizeof(float), stream);
  hipMemsetAsync(cnt, 0, 256, stream);

  // w1 [D=1024][EH=8192] -> w1t [EH][D]
  transpose_cast<<<dim3(256, 32, 1), 256, 0, stream>>>(w1, w1t, 1024, 8192, 0, 0);
  // w2 [E][H=1024][D=1024] -> w2t [E][D][H]
  transpose_cast<<<dim3(32, 32, 8), 256, 0, stream>>>(w2, w2t, 1024, 1024, 1048576L, 1048576L);
  router_kernel<<<256, 256, 0, stream>>>(x, rw, ebias, xb, sel, selw, probs_buf, lse2_buf, cnt, cnt_be);
  offsets_kernel<<<1, 64, 0, stream>>>(cnt, offs, cursor);
  build_lists<<<32, 256, 0, stream>>>(sel, selw, cursor, tok_list, wt_list);
  // worst case sum(ceil(cnt_e/128)) <= 136 row tiles; 8 col tiles
  moe_gemm<false><<<136 * 8, 256, 0, stream>>>(xb, w1t, h, nullptr, tok_list, wt_list, cnt, offs);
  moe_gemm<true><<<136 * 8, 256, 0, stream>>>(h, w2t, nullptr, out, tok_list, wt_list, cnt, offs);
  finalize_kernel<<<1, 256, 0, stream>>>(lse2_buf, probs_buf, cnt, cnt_be, out + 8388608);
}

// Round 3
// 420.681 us; speedup vs baseline: 1.4978x; 1.2096x over previous
//
#include <hip/hip_runtime.h>

typedef unsigned short u16;
typedef unsigned int u32;
typedef __bf16 bf16x8 __attribute__((ext_vector_type(8)));
typedef float f32x4 __attribute__((ext_vector_type(4)));

// Problem constants
#define NTOK   8192      // B*S
#define DDIM   1024
#define NEXP   8
#define HDIM   1024
#define PAIRS  16384     // NTOK * K

// ---------------- helpers ----------------
__device__ __forceinline__ u16 f2bf(float f) {
  union { float f; u32 u; } v; v.f = f;
  u32 r = v.u + 0x7FFFu + ((v.u >> 16) & 1u);   // RNE
  return (u16)(r >> 16);
}

__device__ __forceinline__ f32x4 mfma16(bf16x8 a, bf16x8 b, f32x4 c) {
  return __builtin_amdgcn_mfma_f32_16x16x32_bf16(a, b, c, 0, 0, 0);
}

// async global->LDS gather DMA, 16B per lane, lds dst = base + lane*16
__device__ __forceinline__ void gload16(const void* g, void* l) {
  __builtin_amdgcn_global_load_lds(
      (__attribute__((address_space(1))) void*)g,
      (__attribute__((address_space(3))) void*)l, 16, 0, 0);
}

// ---------------- transpose + cast: out[c][r] = in[r][c] ----------------
__global__ __launch_bounds__(256) void transpose_cast(const float* __restrict__ in,
                                                      u16* __restrict__ out,
                                                      int R, int C,
                                                      long in_zs, long out_zs) {
  __shared__ float tile[32][33];
  long ib = (long)blockIdx.z * in_zs;
  long ob = (long)blockIdx.z * out_zs;
  int r0 = blockIdx.y * 32, c0 = blockIdx.x * 32;
  int tx = threadIdx.x & 31, ty = threadIdx.x >> 5;   // ty in [0,8)
  #pragma unroll
  for (int rr = 0; rr < 32; rr += 8)
    tile[ty + rr][tx] = in[ib + (long)(r0 + ty + rr) * C + c0 + tx];
  __syncthreads();
  #pragma unroll
  for (int rr = 0; rr < 32; rr += 8)
    out[ob + (long)(c0 + ty + rr) * R + r0 + tx] = f2bf(tile[tx][ty + rr]);
}

// ---------------- router: 16 tokens/block, thread = (token, expert, half) ------
// Also emits xb (bf16 cast of x) and TRANSPOSED probs_t[e][t].
__global__ __launch_bounds__(256) void router_kernel(
    const float* __restrict__ x, const float* __restrict__ rw,
    const float* __restrict__ ebias, u16* __restrict__ xb,
    int2* __restrict__ sel, float2* __restrict__ selw,
    float* __restrict__ probs_t, float* __restrict__ lse2_buf,
    u32* __restrict__ cnt, u32* __restrict__ cnt_be) {
  __shared__ float rw_lds[8 * 1028];    // +4 pad
  __shared__ double lg[16][8][2];
  __shared__ u32 cl[8];
  int tid = threadIdx.x;
  int tl = tid >> 4, e = (tid >> 1) & 7, s = tid & 1;
  int t = blockIdx.x * 16 + tl;

  for (int i = tid; i < 8192; i += 256)
    rw_lds[(i >> 10) * 1028 + (i & 1023)] = rw[i];
  if (tid < 8) cl[tid] = 0;
  __syncthreads();

  const float* xr = x + (long)t * DDIM;
  const float* wr = rw_lds + e * 1028;
  u16* xbr = xb + (long)t * DDIM;
  double a0 = 0.0, a1 = 0.0;
  int dbase = s * 512;
  for (int d0 = dbase; d0 < dbase + 512; d0 += 16) {
    float4 x0 = *(const float4*)(xr + d0);
    float4 w0 = *(const float4*)(wr + d0);
    float4 x1 = *(const float4*)(xr + d0 + 4);
    float4 w1v = *(const float4*)(wr + d0 + 4);
    float4 x2 = *(const float4*)(xr + d0 + 8);
    float4 w2v = *(const float4*)(wr + d0 + 8);
    float4 x3 = *(const float4*)(xr + d0 + 12);
    float4 w3 = *(const float4*)(wr + d0 + 12);
    a0 += (double)x0.x * w0.x + (double)x0.y * w0.y + (double)x0.z * w0.z + (double)x0.w * w0.w;
    a1 += (double)x1.x * w1v.x + (double)x1.y * w1v.y + (double)x1.z * w1v.z + (double)x1.w * w1v.w;
    a0 += (double)x2.x * w2v.x + (double)x2.y * w2v.y + (double)x2.z * w2v.z + (double)x2.w * w2v.w;
    a1 += (double)x3.x * w3.x + (double)x3.y * w3.y + (double)x3.z * w3.z + (double)x3.w * w3.w;
    if (e == 0) {
      *(ushort4*)(xbr + d0)     = make_ushort4(f2bf(x0.x), f2bf(x0.y), f2bf(x0.z), f2bf(x0.w));
      *(ushort4*)(xbr + d0 + 4) = make_ushort4(f2bf(x1.x), f2bf(x1.y), f2bf(x1.z), f2bf(x1.w));
      *(ushort4*)(xbr + d0 + 8) = make_ushort4(f2bf(x2.x), f2bf(x2.y), f2bf(x2.z), f2bf(x2.w));
      *(ushort4*)(xbr + d0 +12) = make_ushort4(f2bf(x3.x), f2bf(x3.y), f2bf(x3.z), f2bf(x3.w));
    }
  }
  lg[tl][e][s] = a0 + a1;
  __syncthreads();

  if (tid < 16) {
    int t2 = blockIdx.x * 16 + tid;
    double logit[8]; float p[8]; float score[8];
    for (int ee = 0; ee < 8; ee++) {
      logit[ee] = lg[tid][ee][0] + lg[tid][ee][1];
      p[ee] = (float)(1.0 / (1.0 + exp(-logit[ee])));
      score[ee] = p[ee] + ebias[ee];
      probs_t[ee * NTOK + t2] = p[ee];
    }
    int i0 = 0;
    for (int ee = 1; ee < 8; ee++) if (score[ee] > score[i0]) i0 = ee;
    int i1 = (i0 == 0) ? 1 : 0;
    for (int ee = 0; ee < 8; ee++) if (ee != i0 && score[ee] > score[i1]) i1 = ee;
    float w0 = p[i0], w1 = p[i1];
    float ssum = w0 + w1 + 1e-20f;
    sel[t2] = make_int2(i0, i1);
    selw[t2] = make_float2(w0 / ssum, w1 / ssum);
    double m = logit[0];
    for (int ee = 1; ee < 8; ee++) m = fmax(m, logit[ee]);
    double se = 0.0;
    for (int ee = 0; ee < 8; ee++) se += exp(logit[ee] - m);
    double ls = m + log(se);
    lse2_buf[t2] = (float)(ls * ls);
    atomicAdd(&cl[i0], 1u); atomicAdd(&cl[i1], 1u);
  }
  __syncthreads();
  if (tid < 8) {
    int b = (blockIdx.x * 16) >> 11;   // S = 2048, uniform per block
    atomicAdd(&cnt[tid], cl[tid]);
    atomicAdd(&cnt_be[b * 8 + tid], cl[tid]);
  }
}

// ---------------- prefix offsets (E=8) ----------------
__global__ void offsets_kernel(const u32* __restrict__ cnt, u32* __restrict__ offs,
                               u32* __restrict__ cursor) {
  if (threadIdx.x == 0 && blockIdx.x == 0) {
    u32 a = 0;
    for (int e = 0; e < 8; e++) { offs[e] = a; cursor[e] = a; a += cnt[e]; }
  }
}

// ---------------- build expert-sorted pair lists + inverse map ----------------
__global__ __launch_bounds__(256) void build_lists(
    const int2* __restrict__ sel, const float2* __restrict__ selw,
    u32* __restrict__ cursor, int* __restrict__ tok_list, float* __restrict__ wt_list,
    int* __restrict__ inv) {
  int t = blockIdx.x * 256 + threadIdx.x;   // 8192 tokens
  int2 s = sel[t]; float2 w = selw[t];
  u32 p0 = atomicAdd(&cursor[s.x], 1u);
  tok_list[p0] = t; wt_list[p0] = w.x; inv[2 * t] = (int)p0;
  u32 p1 = atomicAdd(&cursor[s.y], 1u);
  tok_list[p1] = t; wt_list[p1] = w.y; inv[2 * t + 1] = (int)p1;
}

// ---------------- grouped GEMM: 128x128x64 tiles, 4 waves at 64x64 ----------------
// LINEAR staging (m97-style): each gload16 reads lane-ascending contiguous 16B
// chunks (8 rows x 128B per instruction, fully coalesced). LDS is row-major
// [row][kchunk]; the ds_read fragment pattern has a 2x-over-minimum bank
// aliasing (16 banks/instr) which m97 shows is the right trade.
// SECOND=false: h[slot][n] = relu(x[tok] @ w1t_e[n])^2      (A gathered via tok_list)
// SECOND=true : y[slot][n] = wt[slot] * (h[slot] @ w2t_e[n])   (bf16, no atomics)
template <bool SECOND>
__global__ __launch_bounds__(256) void moe_gemm(
    const u16* __restrict__ A, const u16* __restrict__ Bt,
    u16* __restrict__ out16,
    const int* __restrict__ tok_list, const float* __restrict__ wt_list,
    const u32* __restrict__ cnt, const u32* __restrict__ offs) {
  int tn = blockIdx.x & 7;         // 8 col tiles over N=1024
  int tm = blockIdx.x >> 3;        // global row-tile over all experts
  int e = 0, acct = 0;
  while (e < 8) {
    int nt = (int)((cnt[e] + 127u) >> 7);
    if (tm < acct + nt) break;
    acct += nt; e++;
  }
  if (e == 8) return;              // uniform across block
  int m0 = (tm - acct) * 128;
  int off = (int)offs[e];
  int ce  = (int)cnt[e];

  __shared__ uint4 As[1024];       // [row][kchunk], 16 KB
  __shared__ uint4 Bs[1024];

  int tid = threadIdx.x;
  int l = tid & 63, w = tid >> 6;

  // staging pointers: lane-linear. slot p = w*256 + j*64 + l -> row=p>>3, c=p&7
  const u16* agp[4]; const u16* bgp[4];
  #pragma unroll
  for (int j = 0; j < 4; j++) {
    int p = w * 256 + j * 64 + l;
    int row = p >> 3, c = p & 7;
    long arow;
    if (SECOND) {
      arow = (long)(off + m0 + row);
    } else {
      int rr = m0 + row; if (rr > ce - 1) rr = ce - 1;   // clamp padded rows
      arow = (long)tok_list[off + rr];
    }
    agp[j] = A + arow * 1024 + c * 8;
    bgp[j] = Bt + (long)e * 1048576 + (long)(tn * 128 + row) * 1024 + c * 8;
  }

  f32x4 acc[4][4];
  #pragma unroll
  for (int i = 0; i < 4; i++)
    #pragma unroll
    for (int j = 0; j < 4; j++) acc[i][j] = (f32x4){0.f, 0.f, 0.f, 0.f};

  int mr = l & 15, q = l >> 4;
  int wm = (w >> 1) * 64, wn = (w & 1) * 64;

  for (int k0 = 0; k0 < 1024; k0 += 64) {
    #pragma unroll
    for (int j = 0; j < 4; j++) {
      gload16(agp[j], &As[w * 256 + j * 64]);
      gload16(bgp[j], &Bs[w * 256 + j * 64]);
      agp[j] += 64; bgp[j] += 64;
    }
    __syncthreads();
    #pragma unroll
    for (int kk = 0; kk < 2; kk++) {
      int cg = kk * 4 + q;
      bf16x8 af[4], bfr[4];
      #pragma unroll
      for (int i = 0; i < 4; i++) {
        af[i]  = __builtin_bit_cast(bf16x8, As[(wm + i * 16 + mr) * 8 + cg]);
        bfr[i] = __builtin_bit_cast(bf16x8, Bs[(wn + i * 16 + mr) * 8 + cg]);
      }
      #pragma unroll
      for (int i = 0; i < 4; i++)
        #pragma unroll
        for (int j = 0; j < 4; j++)
          acc[i][j] = mfma16(af[i], bfr[j], acc[i][j]);
    }
    __syncthreads();
  }

  // epilogue: C/D layout col=lane&15, row=(lane>>4)*4+reg  [m89-verified]
  #pragma unroll
  for (int i = 0; i < 4; i++) {
    #pragma unroll
    for (int r = 0; r < 4; r++) {
      int rr = wm + i * 16 + q * 4 + r;
      if (m0 + rr >= ce) continue;
      int slot = off + m0 + rr;
      float wgt = SECOND ? wt_list[slot] : 0.f;
      #pragma unroll
      for (int j = 0; j < 4; j++) {
        int cc = tn * 128 + wn + j * 16 + mr;
        float v = acc[i][j][r];
        if (!SECOND) {
          v = fmaxf(v, 0.f); v = v * v;
          out16[(long)slot * 1024 + cc] = f2bf(v);
        } else {
          out16[(long)slot * 1024 + cc] = f2bf(v * wgt);
        }
      }
    }
  }
}

// ---------------- combine: out[t] = y[slot0] + y[slot1] ----------------
__global__ __launch_bounds__(128) void combine_kernel(
    const u16* __restrict__ y, const int* __restrict__ inv,
    float* __restrict__ out) {
  int t = blockIdx.x, tid = threadIdx.x;
  int s0 = inv[2 * t], s1 = inv[2 * t + 1];
  uint4 a = *(const uint4*)(y + (long)s0 * 1024 + tid * 8);
  uint4 b = *(const uint4*)(y + (long)s1 * 1024 + tid * 8);
  float o[8];
  const u32* au = (const u32*)&a;
  const u32* bu = (const u32*)&b;
  #pragma unroll
  for (int i = 0; i < 4; i++) {
    union { u32 u; float f; } lo1, hi1, lo2, hi2;
    lo1.u = au[i] << 16;  hi1.u = au[i] & 0xFFFF0000u;
    lo2.u = bu[i] << 16;  hi2.u = bu[i] & 0xFFFF0000u;
    o[2 * i]     = lo1.f + lo2.f;
    o[2 * i + 1] = hi1.f + hi2.f;
  }
  float* op = out + (long)t * 1024 + tid * 8;
  *(float4*)op       = make_float4(o[0], o[1], o[2], o[3]);
  *(float4*)(op + 4) = make_float4(o[4], o[5], o[6], o[7]);
}

// ---------------- parallel reductions for aux losses ----------------
// blocks 0..31: pe_sum[p] = sum_s probs_t[e][b*2048+s]  (p = b*8+e)
// blocks 32..39: z_part[i] = sum of lse2[i*1024 .. +1024)
__global__ __launch_bounds__(256) void reduce_pe(
    const float* __restrict__ probs_t, const float* __restrict__ lse2,
    float* __restrict__ pe_sum, float* __restrict__ z_part) {
  __shared__ float sd[256];
  int tid = threadIdx.x, blk = blockIdx.x;
  float s = 0.f;
  if (blk < 32) {
    int b = blk >> 3, e = blk & 7;
    const float* p = probs_t + e * NTOK + b * 2048;
    for (int i = tid; i < 2048; i += 256) s += p[i];
  } else {
    const float* p = lse2 + (blk - 32) * 1024;
    for (int i = tid; i < 1024; i += 256) s += p[i];
  }
  sd[tid] = s; __syncthreads();
  for (int st = 128; st > 0; st >>= 1) {
    if (tid < st) sd[tid] += sd[tid + st];
    __syncthreads();
  }
  if (tid == 0) {
    if (blk < 32) pe_sum[blk] = sd[0];
    else z_part[blk - 32] = sd[0];
  }
}

__global__ void finalize_kernel(
    const float* __restrict__ pe_sum, const float* __restrict__ z_part,
    const u32* __restrict__ cnt, const u32* __restrict__ cnt_be,
    float* __restrict__ out_tail) {
  if (threadIdx.x == 0 && blockIdx.x == 0) {
    float z = 0.f;
    for (int i = 0; i < 8; i++) z += z_part[i];
    z /= (float)NTOK;
    float lb = 0.f, clv = 0.f;
    for (int p = 0; p < 32; p++) {
      float psum = pe_sum[p];
      clv += psum;
      float f = (float)cnt_be[p] / 4096.0f;     // S*K
      lb += f * (psum / 2048.0f);               // p_seq mean over S
    }
    lb = 8.0f * lb / 4.0f;                      // E * mean over B
    clv = clv / (float)NTOK;
    out_tail[0] = z;
    out_tail[1] = lb;
    out_tail[2] = clv;
    for (int e2 = 0; e2 < 8; e2++) out_tail[3 + e2] = (float)cnt[e2] / 16384.0f;
  }
}

// ---------------- launch ----------------
extern "C" void kernel_launch(void* const* d_in, const int* in_sizes, int n_in,
                              void* d_out, int out_size, void* d_ws, size_t ws_size,
                              hipStream_t stream) {
  const float* x     = (const float*)d_in[0];
  const float* rw    = (const float*)d_in[1];
  const float* w1    = (const float*)d_in[2];
  const float* w2    = (const float*)d_in[3];
  const float* ebias = (const float*)d_in[4];
  float* out = (float*)d_out;

  char* ws = (char*)d_ws;
  // ws layout (bytes). y (GEMM2 output, 16384*1024*2 = 33,554,432) OVERLAYS
  // xb+w1t which are dead after GEMM1.
  u16*    xb        = (u16*)(ws + 0);                 // 16,777,216
  u16*    w1t       = (u16*)(ws + 16777216);          // 16,777,216
  u16*    y         = (u16*)(ws + 0);                 // overlay, 33,554,432
  u16*    w2t       = (u16*)(ws + 33554432);          // 16,777,216
  u16*    h         = (u16*)(ws + 50331648);          // 16512 rows: 33,816,576
  int*    tok_list  = (int*)(ws + 84148224);          // 65,536
  float*  wt_list   = (float*)(ws + 84213760);        // 65,536
  int2*   sel       = (int2*)(ws + 84279296);         // 65,536
  float2* selw      = (float2*)(ws + 84344832);       // 65,536
  float*  probs_t   = (float*)(ws + 84410368);        // 262,144  [E][T]
  float*  lse2_buf  = (float*)(ws + 84672512);        // 32,768
  int*    inv       = (int*)(ws + 84705280);          // 65,536
  u32*    cnt       = (u32*)(ws + 84770816);          // counters block (512 B)
  u32*    cursor    = cnt + 8;
  u32*    cnt_be    = cnt + 16;   // 32 entries [B][E]
  u32*    offs      = cnt + 48;
  float*  pe_sum    = (float*)(cnt + 56);             // 32 floats
  float*  z_part    = (float*)(cnt + 88);             // 8 floats

  hipMemsetAsync(cnt, 0, 512, stream);

  // w1 [D=1024][EH=8192] -> w1t [EH][D]
  transpose_cast<<<dim3(256, 32, 1), 256, 0, stream>>>(w1, w1t, 1024, 8192, 0, 0);
  // w2 [E][H=1024][D=1024] -> w2t [E][D][H]
  transpose_cast<<<dim3(32, 32, 8), 256, 0, stream>>>(w2, w2t, 1024, 1024, 1048576L, 1048576L);
  router_kernel<<<512, 256, 0, stream>>>(x, rw, ebias, xb, sel, selw, probs_t, lse2_buf, cnt, cnt_be);
  offsets_kernel<<<1, 64, 0, stream>>>(cnt, offs, cursor);
  build_lists<<<32, 256, 0, stream>>>(sel, selw, cursor, tok_list, wt_list, inv);
  // worst case sum(ceil(cnt_e/128)) <= 135 row tiles; 8 col tiles
  moe_gemm<false><<<136 * 8, 256, 0, stream>>>(xb, w1t, h, tok_list, wt_list, cnt, offs);
  moe_gemm<true><<<136 * 8, 256, 0, stream>>>(h, w2t, y, tok_list, wt_list, cnt, offs);
  combine_kernel<<<8192, 128, 0, stream>>>(y, inv, out);
  reduce_pe<<<40, 256, 0, stream>>>(probs_t, lse2_buf, pe_sum, z_part);
  finalize_kernel<<<1, 64, 0, stream>>>(pe_sum, z_part, cnt, cnt_be, out + 8388608);
}

// Round 4
// 376.562 us; speedup vs baseline: 1.6733x; 1.1172x over previous
//
#include <hip/hip_runtime.h>

typedef unsigned short u16;
typedef unsigned int u32;
typedef __bf16 bf16x8 __attribute__((ext_vector_type(8)));
typedef float f32x4 __attribute__((ext_vector_type(4)));

// Problem constants
#define NTOK   8192      // B*S
#define DDIM   1024
#define NEXP   8
#define HDIM   1024
#define PAIRS  16384     // NTOK * K

// ---------------- helpers ----------------
__device__ __forceinline__ u16 f2bf(float f) {
  union { float f; u32 u; } v; v.f = f;
  u32 r = v.u + 0x7FFFu + ((v.u >> 16) & 1u);   // RNE
  return (u16)(r >> 16);
}

__device__ __forceinline__ f32x4 mfma16(bf16x8 a, bf16x8 b, f32x4 c) {
  return __builtin_amdgcn_mfma_f32_16x16x32_bf16(a, b, c, 0, 0, 0);
}

// async global->LDS gather DMA, 16B per lane, lds dst = base + lane*16
__device__ __forceinline__ void gload16(const void* g, void* l) {
  __builtin_amdgcn_global_load_lds(
      (__attribute__((address_space(1))) void*)g,
      (__attribute__((address_space(3))) void*)l, 16, 0, 0);
}

// ---------------- merged transpose+cast of w1 and w2 ----------------
// z<8 : w1t[e][h][d] = w1[d][e*1024+h]   (e = z)
// z>=8: w2t[e][d][h] = w2[e][h][d]       (e = z-8)
__global__ __launch_bounds__(256) void transpose_all(
    const float* __restrict__ w1, const float* __restrict__ w2,
    u16* __restrict__ w1t, u16* __restrict__ w2t) {
  __shared__ float tile[32][33];
  int z = blockIdx.z;
  const float* ib; long rs; u16* ob;
  if (z < 8) { ib = w1 + z * 1024; rs = 8192; ob = w1t + (long)z * 1048576; }
  else       { ib = w2 + (long)(z - 8) * 1048576; rs = 1024; ob = w2t + (long)(z - 8) * 1048576; }
  int r0 = blockIdx.y * 32, c0 = blockIdx.x * 32;
  int tx = threadIdx.x & 31, ty = threadIdx.x >> 5;   // ty in [0,8)
  #pragma unroll
  for (int rr = 0; rr < 32; rr += 8)
    tile[ty + rr][tx] = ib[(long)(r0 + ty + rr) * rs + c0 + tx];
  __syncthreads();
  #pragma unroll
  for (int rr = 0; rr < 32; rr += 8)
    ob[(long)(c0 + ty + rr) * 1024 + r0 + tx] = f2bf(tile[tx][ty + rr]);
}

// ---------------- router: half-wave (32 lanes) per token ----------------
// x read ONCE per token; emits xb (bf16), sel/selw, and loss partials
// (pe_sum[b*8+e], z_sum) via atomics. No probs buffer needed.
__global__ __launch_bounds__(256) void router_kernel(
    const float* __restrict__ x, const float* __restrict__ rw,
    const float* __restrict__ ebias, u16* __restrict__ xb,
    int2* __restrict__ sel, float2* __restrict__ selw,
    u32* __restrict__ cnt, u32* __restrict__ cnt_be,
    float* __restrict__ pe_sum, float* __restrict__ z_sum) {
  __shared__ float rw_lds[8 * 1028];    // +4 pad per row
  __shared__ float pe_loc[8];
  __shared__ float z_loc;
  __shared__ u32 cl[8];
  int tid = threadIdx.x;
  for (int i = tid; i < 8192; i += 256)
    rw_lds[(i >> 10) * 1028 + (i & 1023)] = rw[i];
  if (tid < 8) { pe_loc[tid] = 0.f; cl[tid] = 0u; }
  if (tid == 8) z_loc = 0.f;
  __syncthreads();

  int ht = tid >> 5;          // half-wave id 0..7 -> token slot
  int hl = tid & 31;
  int t = blockIdx.x * 8 + ht;
  const float* xr = x + (long)t * DDIM;
  u16* xbr = xb + (long)t * DDIM;
  double acc[8];
  #pragma unroll
  for (int e = 0; e < 8; e++) acc[e] = 0.0;
  #pragma unroll
  for (int p = 0; p < 8; p++) {
    int d = p * 128 + hl * 4;
    float4 xv = *(const float4*)(xr + d);
    *(ushort4*)(xbr + d) = make_ushort4(f2bf(xv.x), f2bf(xv.y), f2bf(xv.z), f2bf(xv.w));
    #pragma unroll
    for (int e = 0; e < 8; e++) {
      float4 wv = *(const float4*)(rw_lds + e * 1028 + d);
      acc[e] += (double)xv.x * (double)wv.x + (double)xv.y * (double)wv.y
              + (double)xv.z * (double)wv.z + (double)xv.w * (double)wv.w;
    }
  }
  #pragma unroll
  for (int e = 0; e < 8; e++) {
    #pragma unroll
    for (int off = 16; off > 0; off >>= 1)
      acc[e] += __shfl_down(acc[e], off, 32);
  }
  if (hl == 0) {
    double logit[8]; float p8[8], score[8];
    for (int e = 0; e < 8; e++) {
      logit[e] = acc[e];
      p8[e] = (float)(1.0 / (1.0 + exp(-logit[e])));
      score[e] = p8[e] + ebias[e];
    }
    // top-2, ties -> lowest index (lax.top_k is stable)
    int i0 = 0;
    for (int e = 1; e < 8; e++) if (score[e] > score[i0]) i0 = e;
    int i1 = (i0 == 0) ? 1 : 0;
    for (int e = 0; e < 8; e++) if (e != i0 && score[e] > score[i1]) i1 = e;
    float w0 = p8[i0], w1v = p8[i1];
    float ssum = w0 + w1v + 1e-20f;
    sel[t] = make_int2(i0, i1);
    selw[t] = make_float2(w0 / ssum, w1v / ssum);
    double m = logit[0];
    for (int e = 1; e < 8; e++) m = fmax(m, logit[e]);
    double se = 0.0;
    for (int e = 0; e < 8; e++) se += exp(logit[e] - m);
    double ls = m + log(se);
    atomicAdd(&z_loc, (float)(ls * ls));
    for (int e = 0; e < 8; e++) atomicAdd(&pe_loc[e], p8[e]);
    atomicAdd(&cl[i0], 1u); atomicAdd(&cl[i1], 1u);
  }
  __syncthreads();
  if (tid < 8) {
    int b = (int)((blockIdx.x * 8) >> 11);   // S = 2048, uniform per block
    atomicAdd(&cnt[tid], cl[tid]);
    atomicAdd(&cnt_be[b * 8 + tid], cl[tid]);
    atomicAdd(&pe_sum[b * 8 + tid], pe_loc[tid]);
  }
  if (tid == 8) atomicAdd(z_sum, z_loc);
}

// ---------------- prefix offsets (E=8) ----------------
__global__ void offsets_kernel(const u32* __restrict__ cnt, u32* __restrict__ offs,
                               u32* __restrict__ cursor) {
  if (threadIdx.x == 0 && blockIdx.x == 0) {
    u32 a = 0;
    for (int e = 0; e < 8; e++) { offs[e] = a; cursor[e] = a; a += cnt[e]; }
  }
}

// ---------------- build expert-sorted pair lists + inverse map ----------------
__global__ __launch_bounds__(256) void build_lists(
    const int2* __restrict__ sel, const float2* __restrict__ selw,
    u32* __restrict__ cursor, int* __restrict__ tok_list, float* __restrict__ wt_list,
    int* __restrict__ inv) {
  int t = blockIdx.x * 256 + threadIdx.x;   // 8192 tokens
  int2 s = sel[t]; float2 w = selw[t];
  u32 p0 = atomicAdd(&cursor[s.x], 1u);
  tok_list[p0] = t; wt_list[p0] = w.x; inv[2 * t] = (int)p0;
  u32 p1 = atomicAdd(&cursor[s.y], 1u);
  tok_list[p1] = t; wt_list[p1] = w.y; inv[2 * t + 1] = (int)p1;
}

// ---------------- grouped GEMM: 128x128x64 tiles, DOUBLE-BUFFERED DMA ----------------
// One barrier per K-iter: DMA tile k+1 into buf k^1 while computing tile k from
// buf k; the pre-barrier vmcnt(0) drain waits on a load that had the whole
// compute phase to complete. Epilogue repacks through LDS for 128B stores.
// SECOND=false: h[slot][n] = relu(x[tok] @ w1t_e[n])^2      (A gathered via tok_list)
// SECOND=true : y[slot][n] = wt[slot] * (h[slot] @ w2t_e[n])
template <bool SECOND>
__global__ __launch_bounds__(256, 2) void moe_gemm(
    const u16* __restrict__ A, const u16* __restrict__ Bt,
    u16* __restrict__ out16,
    const int* __restrict__ tok_list, const float* __restrict__ wt_list,
    const u32* __restrict__ cnt, const u32* __restrict__ offs) {
  int tn = blockIdx.x & 7;         // 8 col tiles over N=1024 (XCD-pinned -> B slab L2-resident)
  int tm = blockIdx.x >> 3;
  int e = 0, acct = 0;
  while (e < 8) {
    int nt = (int)((cnt[e] + 127u) >> 7);
    if (tm < acct + nt) break;
    acct += nt; e++;
  }
  if (e == 8) return;              // uniform across block
  int m0 = (tm - acct) * 128;
  int off = (int)offs[e];
  int ce  = (int)cnt[e];

  __shared__ uint4 smem[4096];     // 64 KB: A0[0..1023] A1[1024..2047] B0[2048..] B1[3072..]

  int tid = threadIdx.x;
  int l = tid & 63, w = tid >> 6;

  // staging pointers: lane-linear. slot p = w*256 + j*64 + l -> row=p>>3, c=p&7
  const u16* agp[4]; const u16* bgp[4];
  #pragma unroll
  for (int j = 0; j < 4; j++) {
    int p = w * 256 + j * 64 + l;
    int row = p >> 3, c = p & 7;
    long arow;
    if (SECOND) {
      arow = (long)(off + m0 + row);
    } else {
      int rr = m0 + row; if (rr > ce - 1) rr = ce - 1;   // clamp padded rows
      arow = (long)tok_list[off + rr];
    }
    agp[j] = A + arow * 1024 + c * 8;
    bgp[j] = Bt + (long)e * 1048576 + (long)(tn * 128 + row) * 1024 + c * 8;
  }

  // prologue: DMA tile 0 into buffer 0
  #pragma unroll
  for (int j = 0; j < 4; j++) {
    gload16(agp[j], &smem[w * 256 + j * 64]);
    gload16(bgp[j], &smem[2048 + w * 256 + j * 64]);
    agp[j] += 64; bgp[j] += 64;
  }
  __syncthreads();

  f32x4 acc[4][4];
  #pragma unroll
  for (int i = 0; i < 4; i++)
    #pragma unroll
    for (int j = 0; j < 4; j++) acc[i][j] = (f32x4){0.f, 0.f, 0.f, 0.f};

  int mr = l & 15, q = l >> 4;
  int wm = (w >> 1) * 64, wn = (w & 1) * 64;

  for (int k = 0; k < 16; k++) {
    int cur = k & 1, nxt = cur ^ 1;
    if (k < 15) {
      #pragma unroll
      for (int j = 0; j < 4; j++) {
        gload16(agp[j], &smem[nxt * 1024 + w * 256 + j * 64]);
        gload16(bgp[j], &smem[2048 + nxt * 1024 + w * 256 + j * 64]);
        agp[j] += 64; bgp[j] += 64;
      }
    }
    const uint4* Ab = smem + cur * 1024;
    const uint4* Bb = smem + 2048 + cur * 1024;
    #pragma unroll
    for (int kk = 0; kk < 2; kk++) {
      int cg = kk * 4 + q;
      bf16x8 af[4], bfr[4];
      #pragma unroll
      for (int i = 0; i < 4; i++) {
        af[i]  = __builtin_bit_cast(bf16x8, Ab[(wm + i * 16 + mr) * 8 + cg]);
        bfr[i] = __builtin_bit_cast(bf16x8, Bb[(wn + i * 16 + mr) * 8 + cg]);
      }
      #pragma unroll
      for (int i = 0; i < 4; i++)
        #pragma unroll
        for (int j = 0; j < 4; j++)
          acc[i][j] = mfma16(af[i], bfr[j], acc[i][j]);
    }
    __syncthreads();   // drains this iter's DMA (issued ~whole compute phase ago)
  }

  // epilogue: repack wave's 64x64 bf16 tile via LDS (stride 72 u16 = 144B,
  // 16B-aligned rows, ~conflict-free), then 128B-coalesced global stores.
  // C/D layout col=lane&15, row=(lane>>4)*4+reg  [m89-verified]
  u16* ost = (u16*)smem + w * 4608;     // 64 x 72 u16 = 9216 B per wave
  #pragma unroll
  for (int i = 0; i < 4; i++) {
    #pragma unroll
    for (int r = 0; r < 4; r++) {
      int rl = i * 16 + q * 4 + r;
      float wgt = 1.f;
      if (SECOND) {
        int gr = m0 + wm + rl;
        int slot = (gr < ce) ? (off + gr) : 0;
        wgt = wt_list[slot];
      }
      #pragma unroll
      for (int j = 0; j < 4; j++) {
        float v = acc[i][j][r];
        if (!SECOND) { v = fmaxf(v, 0.f); v = v * v; }
        else v *= wgt;
        ost[rl * 72 + j * 16 + mr] = f2bf(v);
      }
    }
  }
  // readback: same wave only -> lgkmcnt handles ordering, no barrier needed
  #pragma unroll
  for (int pr = 0; pr < 8; pr++) {
    int rl = pr * 8 + (l >> 3);
    int c8 = l & 7;
    uint4 v = *(const uint4*)(ost + rl * 72 + c8 * 8);
    int gr = m0 + wm + rl;
    if (gr < ce)
      *(uint4*)(out16 + (long)(off + gr) * 1024 + tn * 128 + wn + c8 * 8) = v;
  }
}

// ---------------- combine: out[t] = y[slot0] + y[slot1] ----------------
__global__ __launch_bounds__(128) void combine_kernel(
    const u16* __restrict__ y, const int* __restrict__ inv,
    float* __restrict__ out) {
  int t = blockIdx.x, tid = threadIdx.x;
  int s0 = inv[2 * t], s1 = inv[2 * t + 1];
  uint4 a = *(const uint4*)(y + (long)s0 * 1024 + tid * 8);
  uint4 b = *(const uint4*)(y + (long)s1 * 1024 + tid * 8);
  float o[8];
  const u32* au = (const u32*)&a;
  const u32* bu = (const u32*)&b;
  #pragma unroll
  for (int i = 0; i < 4; i++) {
    union { u32 u; float f; } lo1, hi1, lo2, hi2;
    lo1.u = au[i] << 16;  hi1.u = au[i] & 0xFFFF0000u;
    lo2.u = bu[i] << 16;  hi2.u = bu[i] & 0xFFFF0000u;
    o[2 * i]     = lo1.f + lo2.f;
    o[2 * i + 1] = hi1.f + hi2.f;
  }
  float* op = out + (long)t * 1024 + tid * 8;
  *(float4*)op       = make_float4(o[0], o[1], o[2], o[3]);
  *(float4*)(op + 4) = make_float4(o[4], o[5], o[6], o[7]);
}

// ---------------- finalize aux losses ----------------
__global__ void finalize_kernel(
    const float* __restrict__ pe_sum, const float* __restrict__ z_sum,
    const u32* __restrict__ cnt, const u32* __restrict__ cnt_be,
    float* __restrict__ out_tail) {
  if (threadIdx.x == 0 && blockIdx.x == 0) {
    float z = z_sum[0] / (float)NTOK;
    float lb = 0.f, clv = 0.f;
    for (int p = 0; p < 32; p++) {
      float psum = pe_sum[p];
      clv += psum;
      float f = (float)cnt_be[p] / 4096.0f;     // S*K
      lb += f * (psum / 2048.0f);               // p_seq mean over S
    }
    lb = 8.0f * lb / 4.0f;                      // E * mean over B
    clv = clv / (float)NTOK;
    out_tail[0] = z;
    out_tail[1] = lb;
    out_tail[2] = clv;
    for (int e2 = 0; e2 < 8; e2++) out_tail[3 + e2] = (float)cnt[e2] / 16384.0f;
  }
}

// ---------------- launch ----------------
extern "C" void kernel_launch(void* const* d_in, const int* in_sizes, int n_in,
                              void* d_out, int out_size, void* d_ws, size_t ws_size,
                              hipStream_t stream) {
  const float* x     = (const float*)d_in[0];
  const float* rw    = (const float*)d_in[1];
  const float* w1    = (const float*)d_in[2];
  const float* w2    = (const float*)d_in[3];
  const float* ebias = (const float*)d_in[4];
  float* out = (float*)d_out;

  char* ws = (char*)d_ws;
  // ws layout (bytes). y (GEMM2 output) OVERLAYS xb+w1t (dead after GEMM1).
  u16*    xb        = (u16*)(ws + 0);                 // 16,777,216
  u16*    w1t       = (u16*)(ws + 16777216);          // 16,777,216
  u16*    y         = (u16*)(ws + 0);                 // overlay, 33,554,432
  u16*    w2t       = (u16*)(ws + 33554432);          // 16,777,216
  u16*    h         = (u16*)(ws + 50331648);          // 16512 rows: 33,816,576
  int*    tok_list  = (int*)(ws + 84148224);          // 65,536
  float*  wt_list   = (float*)(ws + 84213760);        // 65,536
  int2*   sel       = (int2*)(ws + 84279296);         // 65,536
  float2* selw      = (float2*)(ws + 84344832);       // 65,536
  int*    inv       = (int*)(ws + 84705280);          // 65,536
  u32*    cnt       = (u32*)(ws + 84770816);          // counters block (512 B)
  u32*    cursor    = cnt + 8;
  u32*    cnt_be    = cnt + 16;   // 32 entries [B][E]
  u32*    offs      = cnt + 48;
  float*  pe_sum    = (float*)(cnt + 56);             // 32 floats
  float*  z_sum     = (float*)(cnt + 88);             // 1 float

  hipMemsetAsync(cnt, 0, 512, stream);

  transpose_all<<<dim3(32, 32, 16), 256, 0, stream>>>(w1, w2, w1t, w2t);
  router_kernel<<<1024, 256, 0, stream>>>(x, rw, ebias, xb, sel, selw, cnt, cnt_be, pe_sum, z_sum);
  offsets_kernel<<<1, 64, 0, stream>>>(cnt, offs, cursor);
  build_lists<<<32, 256, 0, stream>>>(sel, selw, cursor, tok_list, wt_list, inv);
  // worst case sum(ceil(cnt_e/128)) <= 135 row tiles; 8 col tiles
  moe_gemm<false><<<136 * 8, 256, 0, stream>>>(xb, w1t, h, tok_list, wt_list, cnt, offs);
  moe_gemm<true><<<136 * 8, 256, 0, stream>>>(h, w2t, y, tok_list, wt_list, cnt, offs);
  combine_kernel<<<8192, 128, 0, stream>>>(y, inv, out);
  finalize_kernel<<<1, 64, 0, stream>>>(pe_sum, z_sum, cnt, cnt_be, out + 8388608);
}